// Round 15
// baseline (78.460 us; speedup 1.0000x reference)
//
#include <hip/hip_runtime.h>
#include <hip/hip_bf16.h>
#include <stdint.h>

// AttentionBlock: GroupNorm -> 1x1 conv QKV -> 8-head attention (L=1024, D=64)
//                 -> 1x1 conv proj -> residual add.
// B=8, C=512, L=1024. All heavy math in bf16 MFMA with f32 accum.

#define NB 8
#define NC 512
#define NL 1024
#define NHD 8
#define ND 64

typedef __attribute__((ext_vector_type(4))) float f32x4;
typedef __attribute__((ext_vector_type(8))) short bf16x8;       // MFMA A/B operand (K=32)
typedef __attribute__((ext_vector_type(4))) short bf16x4;       // MFMA A/B operand (K=16)
typedef __attribute__((ext_vector_type(4))) unsigned short u16x4;
typedef __attribute__((ext_vector_type(8))) unsigned short u16x8;

#define MFMA16(a, b, c) __builtin_amdgcn_mfma_f32_16x16x32_bf16((a), (b), (c), 0, 0, 0)

static __device__ __forceinline__ f32x4 mfma_k16(bf16x4 a, bf16x4 b, f32x4 c) {
#if __has_builtin(__builtin_amdgcn_mfma_f32_16x16x16bf16_1k)
  return __builtin_amdgcn_mfma_f32_16x16x16bf16_1k(a, b, c, 0, 0, 0);
#else
  asm("v_mfma_f32_16x16x16_bf16 %0, %1, %2, %0" : "+v"(c) : "v"(a), "v"(b));
  return c;
#endif
}

#if __has_builtin(__builtin_amdgcn_exp2f)
#define EXP2F __builtin_amdgcn_exp2f
#else
#define EXP2F exp2f
#endif

static __device__ __forceinline__ unsigned short f2bf(float f) {
  union { float f; uint32_t u; } v; v.f = f;
  uint32_t r = v.u + 0x7fffu + ((v.u >> 16) & 1u);   // round-to-nearest-even
  return (unsigned short)(r >> 16);
}

static __device__ __forceinline__ short f2bf_h(float f) {
  __hip_bfloat16 h = __float2bfloat16(f);            // HW cvt (RNE)
  return *reinterpret_cast<short*>(&h);
}

static __device__ __forceinline__ void gl_lds16(const unsigned short* g, unsigned short* l) {
  __builtin_amdgcn_global_load_lds(
      (const __attribute__((address_space(1))) void*)g,
      (__attribute__((address_space(3))) void*)l, 16, 0, 0);
}

// ---------------- K1: fused {GroupNorm -> xn_t} + {weights f32 -> bf16} ----------
// blocks [0,256): GroupNorm; blocks [256,1280): weight conversion.
__global__ __launch_bounds__(256) void k_pre(const float* __restrict__ x,
                                             const float* __restrict__ nw,
                                             const float* __restrict__ nb,
                                             const float* __restrict__ qkvw,
                                             const float* __restrict__ pw,
                                             unsigned short* __restrict__ xnt,
                                             unsigned short* __restrict__ qwb,
                                             unsigned short* __restrict__ pwb) {
  if (blockIdx.x >= 256) {
    int i = (blockIdx.x - 256) * 256 + threadIdx.x;
    const int NQ4 = (3 * NC * NC) / 4;
    if (i < NQ4) {
      f32x4 v = ((const f32x4*)qkvw)[i];
      u16x4 o; o.x = f2bf(v.x); o.y = f2bf(v.y); o.z = f2bf(v.z); o.w = f2bf(v.w);
      ((u16x4*)qwb)[i] = o;
    } else {
      int j = i - NQ4;
      f32x4 v = ((const f32x4*)pw)[j];
      u16x4 o; o.x = f2bf(v.x); o.y = f2bf(v.y); o.z = f2bf(v.z); o.w = f2bf(v.w);
      ((u16x4*)pwb)[j] = o;
    }
    return;
  }
  const int b = blockIdx.x >> 5, g = blockIdx.x & 31;
  const float* base = x + ((size_t)b * NC + g * 16) * NL;
  const int t = threadIdx.x;
  f32x4 vals[16];
  float s = 0.f, ss = 0.f;
#pragma unroll
  for (int r = 0; r < 16; ++r) {
    f32x4 v = ((const f32x4*)base)[t + 256 * r];
    vals[r] = v;
    s += v.x + v.y + v.z + v.w;
    ss += v.x * v.x + v.y * v.y + v.z * v.z + v.w * v.w;
  }
#pragma unroll
  for (int m = 1; m < 64; m <<= 1) { s += __shfl_xor(s, m, 64); ss += __shfl_xor(ss, m, 64); }
  __shared__ float red[8];
  const int w = t >> 6;
  if ((t & 63) == 0) { red[w] = s; red[4 + w] = ss; }
  __syncthreads();
  s  = red[0] + red[1] + red[2] + red[3];
  ss = red[4] + red[5] + red[6] + red[7];
  const float mean = s * (1.f / 16384.f);
  const float var  = ss * (1.f / 16384.f) - mean * mean;
  const float inv  = rsqrtf(var + 1e-5f);
  u16x8 ov[4][2];
#pragma unroll
  for (int r = 0; r < 16; ++r) {
    float wcv = nw[g * 16 + r] * inv;
    float bcv = nb[g * 16 + r] - mean * wcv;
    f32x4 v = vals[r];
    ov[0][r >> 3][r & 7] = f2bf(v.x * wcv + bcv);
    ov[1][r >> 3][r & 7] = f2bf(v.y * wcv + bcv);
    ov[2][r >> 3][r & 7] = f2bf(v.z * wcv + bcv);
    ov[3][r >> 3][r & 7] = f2bf(v.w * wcv + bcv);
  }
#pragma unroll
  for (int j = 0; j < 4; ++j) {
    size_t off = ((size_t)b * NL + 4 * t + j) * NC + g * 16;
    *(u16x8*)(xnt + off)     = ov[j][0];
    *(u16x8*)(xnt + off + 8) = ov[j][1];
  }
}

// ---------------- K2: QKV GEMM (BK=64, double-buffered, 1 barrier/step) ----------
// q scaled by (1/sqrt(8))*log2(e)  (folds exp->exp2 in attention); k by 1/sqrt(8).
// v written in slot layout vt[bh][s>>2][c][s&3] so attention can stage it linearly.
__global__ __launch_bounds__(256) void k_qkv(const unsigned short* __restrict__ xnt,
                                             const unsigned short* __restrict__ qwb,
                                             const float* __restrict__ qkvb,
                                             unsigned short* __restrict__ qt,
                                             unsigned short* __restrict__ kt,
                                             unsigned short* __restrict__ vt) {
  __shared__ __align__(16) unsigned short As[2][128 * 64];
  __shared__ __align__(16) unsigned short Bs[2][128 * 64];
  const int m0 = blockIdx.x * 128;  // l
  const int n0 = blockIdx.y * 128;  // o
  const int b = blockIdx.z;
  const int tid = threadIdx.x, lane = tid & 63, w = tid >> 6;
  const int wr = w >> 1, wc = w & 1;
  const int lo = lane & 15, g = lane >> 4;

  int soff[4];
#pragma unroll
  for (int r = 0; r < 4; ++r) {
    int c = (r * 4 + w) * 64 + lane;
    int row = c >> 3, lc = (c & 7) ^ (row & 7);
    soff[r] = row * NC + lc * 8;
  }
  const unsigned short* Ap = xnt + (size_t)b * NL * NC + (size_t)m0 * NC;
  const unsigned short* Bp = qwb + (size_t)n0 * NC;

  f32x4 acc[4][4];
#pragma unroll
  for (int mi = 0; mi < 4; ++mi)
#pragma unroll
    for (int ni = 0; ni < 4; ++ni) acc[mi][ni] = (f32x4){0.f, 0.f, 0.f, 0.f};

  // prologue: stage k-step 0 into buffer 0
#pragma unroll
  for (int r = 0; r < 4; ++r) {
    gl_lds16(Ap + soff[r], &As[0][(r * 4 + w) * 512]);
    gl_lds16(Bp + soff[r], &Bs[0][(r * 4 + w) * 512]);
  }
  Ap += 64; Bp += 64;

#define QKV_KS(BUF, KS)                                                       \
  {                                                                           \
    bf16x8 af[4], bfr[4];                                                     \
    _Pragma("unroll")                                                         \
    for (int mi = 0; mi < 4; ++mi) {                                          \
      int row = wr * 64 + mi * 16 + lo;                                       \
      int ph = (g + (KS) * 4) ^ (row & 7);                                    \
      af[mi] = *(const bf16x8*)&As[BUF][row * 64 + ph * 8];                   \
    }                                                                         \
    _Pragma("unroll")                                                         \
    for (int ni = 0; ni < 4; ++ni) {                                          \
      int row = wc * 64 + ni * 16 + lo;                                       \
      int ph = (g + (KS) * 4) ^ (row & 7);                                    \
      bfr[ni] = *(const bf16x8*)&Bs[BUF][row * 64 + ph * 8];                  \
    }                                                                         \
    _Pragma("unroll")                                                         \
    for (int mi = 0; mi < 4; ++mi)                                            \
      _Pragma("unroll")                                                       \
      for (int ni = 0; ni < 4; ++ni)                                          \
        acc[mi][ni] = MFMA16(af[mi], bfr[ni], acc[mi][ni]);                   \
  }

#define QKV_STEP(BUF, LAST)                                                   \
  {                                                                           \
    __syncthreads();                                                          \
    if (!(LAST)) {                                                            \
      _Pragma("unroll")                                                       \
      for (int r = 0; r < 4; ++r)                                             \
        gl_lds16(Ap + soff[r], &As[(BUF) ^ 1][(r * 4 + w) * 512]);            \
    }                                                                         \
    QKV_KS(BUF, 0);                                                           \
    if (!(LAST)) {                                                            \
      _Pragma("unroll")                                                       \
      for (int r = 0; r < 4; ++r)                                             \
        gl_lds16(Bp + soff[r], &Bs[(BUF) ^ 1][(r * 4 + w) * 512]);            \
      Ap += 64; Bp += 64;                                                     \
    }                                                                         \
    QKV_KS(BUF, 1);                                                           \
  }

  for (int it = 0; it < 8; it += 2) {
    QKV_STEP(0, false);
    QKV_STEP(1, it == 6);
  }
#undef QKV_STEP
#undef QKV_KS

#pragma unroll
  for (int ni = 0; ni < 4; ++ni) {
    int o = n0 + wc * 64 + ni * 16 + lo;
    int head = o / 192, rem = o - head * 192;
    int type = rem >> 6, ch = rem & 63;
    float bias = qkvb[o];
#pragma unroll
    for (int mi = 0; mi < 4; ++mi) {
      int l0 = m0 + wr * 64 + mi * 16 + (g << 2);
      if (type == 2) {
        u16x4 pk;
#pragma unroll
        for (int i = 0; i < 4; ++i) pk[i] = f2bf(acc[mi][ni][i] + bias);
        *(u16x4*)&vt[(((size_t)(b * NHD + head) * 256 + (l0 >> 2)) * ND + ch) * 4] = pk;
      } else {
        const float sc = (type == 0)
            ? (0.35355339059327373f * 1.4426950408889634f)   // q: fold log2(e)
            : 0.35355339059327373f;                          // k
        unsigned short* dst =
            (type == 0 ? qt : kt) + ((size_t)(b * NHD + head) * NL + l0) * ND + ch;
#pragma unroll
        for (int i = 0; i < 4; ++i)
          dst[i * ND] = f2bf((acc[mi][ni][i] + bias) * sc);
      }
    }
  }
}

// ---------------- K3: flash attention (32 t-rows/wave, 3-deep counted-vmcnt) ------
// KVBLK=64, THREE staging buffers: tile t+2 is issued while computing t, so at
// the tile-top barrier only stage(t) (issued two phases ago) must have landed ->
// s_waitcnt vmcnt(4) keeps stage(t+1)'s 4 loads in flight ACROSS the barrier
// (T4: never drain to 0 in the loop). Raw s_barrier (no implicit drain) +
// sched_barrier(0) fence (rule 18). Per-wave ledger: 4 gl_lds per stage;
// steady-state outstanding at barrier = 8 -> vmcnt(4) retires exactly stage(t).
// No-max softmax (S log2-domain); l via MFMA against ones (lane-local).
__global__ __launch_bounds__(256) void k_attn(const unsigned short* __restrict__ qt,
                                              const unsigned short* __restrict__ kt,
                                              const unsigned short* __restrict__ vt,
                                              unsigned short* __restrict__ abuf) {
  __shared__ __align__(16) unsigned short Ks[3][64 * 64];
  __shared__ __align__(16) unsigned short Vs[3][64 * 64];
  const int bid = blockIdx.x;                  // 512 blocks
  const int bh = (bid & 7) * 8 + (bid >> 6);   // all 8 t-blocks of a bh on one XCD
  const int tb = (bid >> 3) & 7;
  const int tid = threadIdx.x, lane = tid & 63, w = tid >> 6;
  const int lo = lane & 15, g = lane >> 4;
  const int t0 = tb * 128 + w * 32;            // this wave's 32 t-rows
  const unsigned short* qb = qt + (size_t)bh * NL * ND;

  int koff[2], voff[2];
#pragma unroll
  for (int r = 0; r < 2; ++r) {
    int c = (r * 4 + w) * 64 + lane;
    int row = c >> 3, lc = (c & 7) ^ (row & 7);
    koff[r] = row * ND + lc * 8;
    voff[r] = c * 8;
  }
  // K-frag base: addr(sblk, ks) = sblk*1024 + lo*64 + ((ks*4+g)^(lo&7))*8
  const int e0 = lo * 64 + ((g ^ (lo & 7)) * 8);
  const int e1 = lo * 64 + (((4 + g) ^ (lo & 7)) * 8);
  // V-frag base: addr(sblk, ci) = sblk*1024 + ci*64 + g*256 + lo*4
  const int vbase = g * 256 + lo * 4;

  const unsigned short* kst = kt + (size_t)bh * NL * ND;
  const unsigned short* vst = vt + (size_t)bh * NL * ND;

  bf16x8 qf[2][2];
#pragma unroll
  for (int h = 0; h < 2; ++h)
#pragma unroll
    for (int ks = 0; ks < 2; ++ks)
      qf[h][ks] = *(const bf16x8*)&qb[(size_t)(t0 + h * 16 + lo) * ND + ks * 32 + g * 8];

  bf16x4 vones;
#pragma unroll
  for (int j = 0; j < 4; ++j) vones[j] = (short)0x3F80;   // bf16 1.0

  f32x4 pv[2][4];
#pragma unroll
  for (int h = 0; h < 2; ++h)
#pragma unroll
    for (int ci = 0; ci < 4; ++ci) pv[h][ci] = (f32x4){0.f, 0.f, 0.f, 0.f};
  f32x4 lacc[2];
  lacc[0] = (f32x4){0.f, 0.f, 0.f, 0.f};
  lacc[1] = (f32x4){0.f, 0.f, 0.f, 0.f};

  // prologue: stage tiles 0 and 1 into buffers 0 and 1 (8 gl_lds/wave in flight)
#pragma unroll
  for (int p = 0; p < 2; ++p) {
    gl_lds16(kst + koff[0], &Ks[p][w * 512]);
    gl_lds16(kst + koff[1], &Ks[p][(4 + w) * 512]);
    gl_lds16(vst + voff[0], &Vs[p][w * 512]);
    gl_lds16(vst + voff[1], &Vs[p][(4 + w) * 512]);
    kst += 4096; vst += 4096;
  }

#define ATTN_BODY(BUF)                                                        \
  {                                                                           \
    f32x4 sacc[2][4];                                                         \
    _Pragma("unroll")                                                         \
    for (int h = 0; h < 2; ++h)                                               \
      _Pragma("unroll")                                                       \
      for (int sblk = 0; sblk < 4; ++sblk)                                    \
        sacc[h][sblk] = (f32x4){0.f, 0.f, 0.f, 0.f};                          \
    __builtin_amdgcn_s_setprio(1);                                            \
    _Pragma("unroll")                                                         \
    for (int sblk = 0; sblk < 4; ++sblk) {                                    \
      bf16x8 kf = *(const bf16x8*)&Ks[BUF][sblk * 1024 + e0];                 \
      sacc[0][sblk] = MFMA16(kf, qf[0][0], sacc[0][sblk]);                    \
      sacc[1][sblk] = MFMA16(kf, qf[1][0], sacc[1][sblk]);                    \
    }                                                                         \
    _Pragma("unroll")                                                         \
    for (int sblk = 0; sblk < 4; ++sblk) {                                    \
      bf16x8 kf = *(const bf16x8*)&Ks[BUF][sblk * 1024 + e1];                 \
      sacc[0][sblk] = MFMA16(kf, qf[0][1], sacc[0][sblk]);                    \
      sacc[1][sblk] = MFMA16(kf, qf[1][1], sacc[1][sblk]);                    \
    }                                                                         \
    __builtin_amdgcn_s_setprio(0);                                            \
    _Pragma("unroll")                                                         \
    for (int sblk = 0; sblk < 4; ++sblk) {                                    \
      float a0 = EXP2F(sacc[0][sblk][0]);                                     \
      float a1 = EXP2F(sacc[0][sblk][1]);                                     \
      float a2 = EXP2F(sacc[0][sblk][2]);                                     \
      float a3 = EXP2F(sacc[0][sblk][3]);                                     \
      bf16x4 pf0;                                                             \
      pf0[0] = f2bf_h(a0); pf0[1] = f2bf_h(a1);                               \
      pf0[2] = f2bf_h(a2); pf0[3] = f2bf_h(a3);                               \
      float b0 = EXP2F(sacc[1][sblk][0]);                                     \
      float b1 = EXP2F(sacc[1][sblk][1]);                                     \
      float b2 = EXP2F(sacc[1][sblk][2]);                                     \
      float b3 = EXP2F(sacc[1][sblk][3]);                                     \
      bf16x4 pf1;                                                             \
      pf1[0] = f2bf_h(b0); pf1[1] = f2bf_h(b1);                               \
      pf1[2] = f2bf_h(b2); pf1[3] = f2bf_h(b3);                               \
      __builtin_amdgcn_s_setprio(1);                                          \
      lacc[0] = mfma_k16(pf0, vones, lacc[0]);                                \
      lacc[1] = mfma_k16(pf1, vones, lacc[1]);                                \
      _Pragma("unroll")                                                       \
      for (int ci = 0; ci < 4; ++ci) {                                        \
        bf16x4 vf = *(const bf16x4*)&Vs[BUF][sblk * 1024 + ci * 64 + vbase];  \
        pv[0][ci] = mfma_k16(pf0, vf, pv[0][ci]);                             \
        pv[1][ci] = mfma_k16(pf1, vf, pv[1][ci]);                             \
      }                                                                       \
      __builtin_amdgcn_s_setprio(0);                                          \
    }                                                                         \
  }

#pragma unroll
  for (int it = 0; it < 16; ++it) {
    const int buf = it % 3;
    if (it < 15) {
      asm volatile("s_waitcnt vmcnt(4)" ::: "memory");   // stage(it) landed; stage(it+1) in flight
    } else {
      asm volatile("s_waitcnt vmcnt(0)" ::: "memory");   // tail: drain last stage
    }
    __builtin_amdgcn_s_barrier();
    __builtin_amdgcn_sched_barrier(0);
    if (it < 14) {
      const int nb = (it + 2) % 3;
      gl_lds16(kst + koff[0], &Ks[nb][w * 512]);
      gl_lds16(kst + koff[1], &Ks[nb][(4 + w) * 512]);
      gl_lds16(vst + voff[0], &Vs[nb][w * 512]);
      gl_lds16(vst + voff[1], &Vs[nb][(4 + w) * 512]);
      kst += 4096; vst += 4096;
    }
    ATTN_BODY(buf);
  }
#undef ATTN_BODY

  // epilogue: lacc[h][i] is the row-sum for t-row t0+h*16+g*4+i (lane-local).
#pragma unroll
  for (int h = 0; h < 2; ++h) {
    float li[4];
#pragma unroll
    for (int i = 0; i < 4; ++i) li[i] = 1.0f / lacc[h][i];
#pragma unroll
    for (int ci = 0; ci < 4; ++ci)
#pragma unroll
      for (int i = 0; i < 4; ++i) {
        int tl = t0 + h * 16 + g * 4 + i;
        abuf[((size_t)bh * NL + tl) * ND + ci * 16 + lo] = f2bf_h(pv[h][ci][i] * li[i]);
      }
  }
}

// ---------------- K4: proj GEMM + bias + residual (BK=64 dbuf, 1 barrier/step) ----
__global__ __launch_bounds__(256) void k_proj(const unsigned short* __restrict__ abuf,
                                              const unsigned short* __restrict__ pwb,
                                              const float* __restrict__ pb,
                                              const float* __restrict__ x,
                                              float* __restrict__ out) {
  __shared__ __align__(16) unsigned short As[2][128 * 64];
  __shared__ __align__(16) unsigned short Bs[2][128 * 64];
  const int m0 = blockIdx.x * 128;  // o
  const int n0 = blockIdx.y * 128;  // l
  const int b = blockIdx.z;
  const int tid = threadIdx.x, lane = tid & 63, w = tid >> 6;
  const int wr = w >> 1, wc = w & 1;
  const int lo = lane & 15, g = lane >> 4;

  int aoff[4], boff[4];
#pragma unroll
  for (int r = 0; r < 4; ++r) {
    int c = (r * 4 + w) * 64 + lane;
    int row = c >> 3, lc = (c & 7) ^ (row & 7);
    aoff[r] = row * NC + lc * 8;
    boff[r] = row * ND + lc * 8;
  }
  const unsigned short* Ap = pwb + (size_t)m0 * NC;
  const unsigned short* Bp = abuf + ((size_t)(b * NHD) * NL + n0) * ND;  // +head*NL*ND per step

  f32x4 acc[4][4];
#pragma unroll
  for (int mi = 0; mi < 4; ++mi)
#pragma unroll
    for (int ni = 0; ni < 4; ++ni) acc[mi][ni] = (f32x4){0.f, 0.f, 0.f, 0.f};

  // prologue: stage k-step 0 into buffer 0
#pragma unroll
  for (int r = 0; r < 4; ++r) {
    gl_lds16(Ap + aoff[r], &As[0][(r * 4 + w) * 512]);
    gl_lds16(Bp + boff[r], &Bs[0][(r * 4 + w) * 512]);
  }
  Ap += 64; Bp += (size_t)NL * ND;

#define PROJ_KS(BUF, KS)                                                      \
  {                                                                           \
    bf16x8 af[4], bfr[4];                                                     \
    _Pragma("unroll")                                                         \
    for (int mi = 0; mi < 4; ++mi) {                                          \
      int row = wr * 64 + mi * 16 + lo;                                       \
      int ph = (g + (KS) * 4) ^ (row & 7);                                    \
      af[mi] = *(const bf16x8*)&As[BUF][row * 64 + ph * 8];                   \
    }                                                                         \
    _Pragma("unroll")                                                         \
    for (int ni = 0; ni < 4; ++ni) {                                          \
      int row = wc * 64 + ni * 16 + lo;                                       \
      int ph = (g + (KS) * 4) ^ (row & 7);                                    \
      bfr[ni] = *(const bf16x8*)&Bs[BUF][row * 64 + ph * 8];                  \
    }                                                                         \
    _Pragma("unroll")                                                         \
    for (int mi = 0; mi < 4; ++mi)                                            \
      _Pragma("unroll")                                                       \
      for (int ni = 0; ni < 4; ++ni)                                          \
        acc[mi][ni] = MFMA16(af[mi], bfr[ni], acc[mi][ni]);                   \
  }

#define PROJ_STEP(BUF, LAST)                                                  \
  {                                                                           \
    __syncthreads();                                                          \
    if (!(LAST)) {                                                            \
      _Pragma("unroll")                                                       \
      for (int r = 0; r < 4; ++r)                                             \
        gl_lds16(Ap + aoff[r], &As[(BUF) ^ 1][(r * 4 + w) * 512]);            \
    }                                                                         \
    PROJ_KS(BUF, 0);                                                          \
    if (!(LAST)) {                                                            \
      _Pragma("unroll")                                                       \
      for (int r = 0; r < 4; ++r)                                             \
        gl_lds16(Bp + boff[r], &Bs[(BUF) ^ 1][(r * 4 + w) * 512]);            \
      Ap += 64; Bp += (size_t)NL * ND;                                        \
    }                                                                         \
    PROJ_KS(BUF, 1);                                                          \
  }

  for (int it = 0; it < 8; it += 2) {
    PROJ_STEP(0, false);
    PROJ_STEP(1, it == 6);
  }
#undef PROJ_STEP
#undef PROJ_KS

#pragma unroll
  for (int mi = 0; mi < 4; ++mi)
#pragma unroll
    for (int i = 0; i < 4; ++i) {
      int o = m0 + wr * 64 + mi * 16 + g * 4 + i;
      float pbv = pb[o];
#pragma unroll
      for (int ni = 0; ni < 4; ++ni) {
        int l = n0 + wc * 64 + ni * 16 + lo;
        size_t idx = ((size_t)b * NC + o) * NL + l;
        out[idx] = x[idx] + acc[mi][ni][i] + pbv;
      }
    }
}

extern "C" void kernel_launch(void* const* d_in, const int* in_sizes, int n_in,
                              void* d_out, int out_size, void* d_ws, size_t ws_size,
                              hipStream_t stream) {
  const float* x    = (const float*)d_in[0];
  const float* nw   = (const float*)d_in[1];
  const float* nb   = (const float*)d_in[2];
  const float* qkvw = (const float*)d_in[3];
  const float* qkvb = (const float*)d_in[4];
  const float* pw   = (const float*)d_in[5];
  const float* pb   = (const float*)d_in[6];
  float* out = (float*)d_out;

  char* ws = (char*)d_ws;
  unsigned short* xnt  = (unsigned short*)(ws);
  unsigned short* abuf = (unsigned short*)(ws);             // overlay (xnt dead after k_qkv)
  unsigned short* qwb  = (unsigned short*)(ws + 8388608);
  unsigned short* pwb  = (unsigned short*)(ws + 9961472);
  unsigned short* qt   = (unsigned short*)(ws + 10485760);
  unsigned short* kt   = (unsigned short*)(ws + 18874368);
  unsigned short* vt   = (unsigned short*)(ws + 27262976);

  k_pre<<<1280, 256, 0, stream>>>(x, nw, nb, qkvw, pw, xnt, qwb, pwb);
  k_qkv<<<dim3(8, 12, 8), 256, 0, stream>>>(xnt, qwb, qkvb, qt, kt, vt);
  k_attn<<<512, 256, 0, stream>>>(qt, kt, vt, abuf);
  k_proj<<<dim3(4, 8, 8), 256, 0, stream>>>(abuf, pwb, pb, x, out);
}

// Round 16
// 77.693 us; speedup vs baseline: 1.0099x; 1.0099x over previous
//
#include <hip/hip_runtime.h>
#include <hip/hip_bf16.h>
#include <stdint.h>

// AttentionBlock: GroupNorm -> 1x1 conv QKV -> 8-head attention (L=1024, D=64)
//                 -> 1x1 conv proj -> residual add.
// B=8, C=512, L=1024. All heavy math in bf16 MFMA with f32 accum.
// Round-16: revert to round-14 best-known (77.9 us). Round-15's 3-deep
// counted-vmcnt pipeline was neutral (T4 regime gate: needs 8-phase schedule).

#define NB 8
#define NC 512
#define NL 1024
#define NHD 8
#define ND 64

typedef __attribute__((ext_vector_type(4))) float f32x4;
typedef __attribute__((ext_vector_type(8))) short bf16x8;       // MFMA A/B operand (K=32)
typedef __attribute__((ext_vector_type(4))) short bf16x4;       // MFMA A/B operand (K=16)
typedef __attribute__((ext_vector_type(4))) unsigned short u16x4;
typedef __attribute__((ext_vector_type(8))) unsigned short u16x8;

#define MFMA16(a, b, c) __builtin_amdgcn_mfma_f32_16x16x32_bf16((a), (b), (c), 0, 0, 0)

static __device__ __forceinline__ f32x4 mfma_k16(bf16x4 a, bf16x4 b, f32x4 c) {
#if __has_builtin(__builtin_amdgcn_mfma_f32_16x16x16bf16_1k)
  return __builtin_amdgcn_mfma_f32_16x16x16bf16_1k(a, b, c, 0, 0, 0);
#else
  asm("v_mfma_f32_16x16x16_bf16 %0, %1, %2, %0" : "+v"(c) : "v"(a), "v"(b));
  return c;
#endif
}

#if __has_builtin(__builtin_amdgcn_exp2f)
#define EXP2F __builtin_amdgcn_exp2f
#else
#define EXP2F exp2f
#endif

static __device__ __forceinline__ unsigned short f2bf(float f) {
  union { float f; uint32_t u; } v; v.f = f;
  uint32_t r = v.u + 0x7fffu + ((v.u >> 16) & 1u);   // round-to-nearest-even
  return (unsigned short)(r >> 16);
}

static __device__ __forceinline__ short f2bf_h(float f) {
  __hip_bfloat16 h = __float2bfloat16(f);            // HW cvt (RNE)
  return *reinterpret_cast<short*>(&h);
}

static __device__ __forceinline__ void gl_lds16(const unsigned short* g, unsigned short* l) {
  __builtin_amdgcn_global_load_lds(
      (const __attribute__((address_space(1))) void*)g,
      (__attribute__((address_space(3))) void*)l, 16, 0, 0);
}

// ---------------- K1: fused {GroupNorm -> xn_t} + {weights f32 -> bf16} ----------
// blocks [0,256): GroupNorm; blocks [256,1280): weight conversion.
__global__ __launch_bounds__(256) void k_pre(const float* __restrict__ x,
                                             const float* __restrict__ nw,
                                             const float* __restrict__ nb,
                                             const float* __restrict__ qkvw,
                                             const float* __restrict__ pw,
                                             unsigned short* __restrict__ xnt,
                                             unsigned short* __restrict__ qwb,
                                             unsigned short* __restrict__ pwb) {
  if (blockIdx.x >= 256) {
    int i = (blockIdx.x - 256) * 256 + threadIdx.x;
    const int NQ4 = (3 * NC * NC) / 4;
    if (i < NQ4) {
      f32x4 v = ((const f32x4*)qkvw)[i];
      u16x4 o; o.x = f2bf(v.x); o.y = f2bf(v.y); o.z = f2bf(v.z); o.w = f2bf(v.w);
      ((u16x4*)qwb)[i] = o;
    } else {
      int j = i - NQ4;
      f32x4 v = ((const f32x4*)pw)[j];
      u16x4 o; o.x = f2bf(v.x); o.y = f2bf(v.y); o.z = f2bf(v.z); o.w = f2bf(v.w);
      ((u16x4*)pwb)[j] = o;
    }
    return;
  }
  const int b = blockIdx.x >> 5, g = blockIdx.x & 31;
  const float* base = x + ((size_t)b * NC + g * 16) * NL;
  const int t = threadIdx.x;
  f32x4 vals[16];
  float s = 0.f, ss = 0.f;
#pragma unroll
  for (int r = 0; r < 16; ++r) {
    f32x4 v = ((const f32x4*)base)[t + 256 * r];
    vals[r] = v;
    s += v.x + v.y + v.z + v.w;
    ss += v.x * v.x + v.y * v.y + v.z * v.z + v.w * v.w;
  }
#pragma unroll
  for (int m = 1; m < 64; m <<= 1) { s += __shfl_xor(s, m, 64); ss += __shfl_xor(ss, m, 64); }
  __shared__ float red[8];
  const int w = t >> 6;
  if ((t & 63) == 0) { red[w] = s; red[4 + w] = ss; }
  __syncthreads();
  s  = red[0] + red[1] + red[2] + red[3];
  ss = red[4] + red[5] + red[6] + red[7];
  const float mean = s * (1.f / 16384.f);
  const float var  = ss * (1.f / 16384.f) - mean * mean;
  const float inv  = rsqrtf(var + 1e-5f);
  u16x8 ov[4][2];
#pragma unroll
  for (int r = 0; r < 16; ++r) {
    float wcv = nw[g * 16 + r] * inv;
    float bcv = nb[g * 16 + r] - mean * wcv;
    f32x4 v = vals[r];
    ov[0][r >> 3][r & 7] = f2bf(v.x * wcv + bcv);
    ov[1][r >> 3][r & 7] = f2bf(v.y * wcv + bcv);
    ov[2][r >> 3][r & 7] = f2bf(v.z * wcv + bcv);
    ov[3][r >> 3][r & 7] = f2bf(v.w * wcv + bcv);
  }
#pragma unroll
  for (int j = 0; j < 4; ++j) {
    size_t off = ((size_t)b * NL + 4 * t + j) * NC + g * 16;
    *(u16x8*)(xnt + off)     = ov[j][0];
    *(u16x8*)(xnt + off + 8) = ov[j][1];
  }
}

// ---------------- K2: QKV GEMM (BK=64, double-buffered, 1 barrier/step) ----------
// q scaled by (1/sqrt(8))*log2(e)  (folds exp->exp2 in attention); k by 1/sqrt(8).
// v written in slot layout vt[bh][s>>2][c][s&3] so attention can stage it linearly.
// Staggered prefetch (A after barrier, B between ks-halves): 8 barriers instead
// of 16, and loads drain one full compute phase after issue (k_attn's pattern).
__global__ __launch_bounds__(256) void k_qkv(const unsigned short* __restrict__ xnt,
                                             const unsigned short* __restrict__ qwb,
                                             const float* __restrict__ qkvb,
                                             unsigned short* __restrict__ qt,
                                             unsigned short* __restrict__ kt,
                                             unsigned short* __restrict__ vt) {
  __shared__ __align__(16) unsigned short As[2][128 * 64];
  __shared__ __align__(16) unsigned short Bs[2][128 * 64];
  const int m0 = blockIdx.x * 128;  // l
  const int n0 = blockIdx.y * 128;  // o
  const int b = blockIdx.z;
  const int tid = threadIdx.x, lane = tid & 63, w = tid >> 6;
  const int wr = w >> 1, wc = w & 1;
  const int lo = lane & 15, g = lane >> 4;

  int soff[4];
#pragma unroll
  for (int r = 0; r < 4; ++r) {
    int c = (r * 4 + w) * 64 + lane;
    int row = c >> 3, lc = (c & 7) ^ (row & 7);
    soff[r] = row * NC + lc * 8;
  }
  const unsigned short* Ap = xnt + (size_t)b * NL * NC + (size_t)m0 * NC;
  const unsigned short* Bp = qwb + (size_t)n0 * NC;

  f32x4 acc[4][4];
#pragma unroll
  for (int mi = 0; mi < 4; ++mi)
#pragma unroll
    for (int ni = 0; ni < 4; ++ni) acc[mi][ni] = (f32x4){0.f, 0.f, 0.f, 0.f};

  // prologue: stage k-step 0 into buffer 0
#pragma unroll
  for (int r = 0; r < 4; ++r) {
    gl_lds16(Ap + soff[r], &As[0][(r * 4 + w) * 512]);
    gl_lds16(Bp + soff[r], &Bs[0][(r * 4 + w) * 512]);
  }
  Ap += 64; Bp += 64;

#define QKV_KS(BUF, KS)                                                       \
  {                                                                           \
    bf16x8 af[4], bfr[4];                                                     \
    _Pragma("unroll")                                                         \
    for (int mi = 0; mi < 4; ++mi) {                                          \
      int row = wr * 64 + mi * 16 + lo;                                       \
      int ph = (g + (KS) * 4) ^ (row & 7);                                    \
      af[mi] = *(const bf16x8*)&As[BUF][row * 64 + ph * 8];                   \
    }                                                                         \
    _Pragma("unroll")                                                         \
    for (int ni = 0; ni < 4; ++ni) {                                          \
      int row = wc * 64 + ni * 16 + lo;                                       \
      int ph = (g + (KS) * 4) ^ (row & 7);                                    \
      bfr[ni] = *(const bf16x8*)&Bs[BUF][row * 64 + ph * 8];                  \
    }                                                                         \
    _Pragma("unroll")                                                         \
    for (int mi = 0; mi < 4; ++mi)                                            \
      _Pragma("unroll")                                                       \
      for (int ni = 0; ni < 4; ++ni)                                          \
        acc[mi][ni] = MFMA16(af[mi], bfr[ni], acc[mi][ni]);                   \
  }

#define QKV_STEP(BUF, LAST)                                                   \
  {                                                                           \
    __syncthreads();                                                          \
    if (!(LAST)) {                                                            \
      _Pragma("unroll")                                                       \
      for (int r = 0; r < 4; ++r)                                             \
        gl_lds16(Ap + soff[r], &As[(BUF) ^ 1][(r * 4 + w) * 512]);            \
    }                                                                         \
    QKV_KS(BUF, 0);                                                           \
    if (!(LAST)) {                                                            \
      _Pragma("unroll")                                                       \
      for (int r = 0; r < 4; ++r)                                             \
        gl_lds16(Bp + soff[r], &Bs[(BUF) ^ 1][(r * 4 + w) * 512]);            \
      Ap += 64; Bp += 64;                                                     \
    }                                                                         \
    QKV_KS(BUF, 1);                                                           \
  }

  for (int it = 0; it < 8; it += 2) {
    QKV_STEP(0, false);
    QKV_STEP(1, it == 6);
  }
#undef QKV_STEP
#undef QKV_KS

#pragma unroll
  for (int ni = 0; ni < 4; ++ni) {
    int o = n0 + wc * 64 + ni * 16 + lo;
    int head = o / 192, rem = o - head * 192;
    int type = rem >> 6, ch = rem & 63;
    float bias = qkvb[o];
#pragma unroll
    for (int mi = 0; mi < 4; ++mi) {
      int l0 = m0 + wr * 64 + mi * 16 + (g << 2);
      if (type == 2) {
        u16x4 pk;
#pragma unroll
        for (int i = 0; i < 4; ++i) pk[i] = f2bf(acc[mi][ni][i] + bias);
        *(u16x4*)&vt[(((size_t)(b * NHD + head) * 256 + (l0 >> 2)) * ND + ch) * 4] = pk;
      } else {
        const float sc = (type == 0)
            ? (0.35355339059327373f * 1.4426950408889634f)   // q: fold log2(e)
            : 0.35355339059327373f;                          // k
        unsigned short* dst =
            (type == 0 ? qt : kt) + ((size_t)(b * NHD + head) * NL + l0) * ND + ch;
#pragma unroll
        for (int i = 0; i < 4; ++i)
          dst[i * ND] = f2bf((acc[mi][ni][i] + bias) * sc);
      }
    }
  }
}

// ---------------- K3: flash attention (32 t-rows/wave, KVBLK=128) ----------------
// 128-s K/V tiles staged per barrier (8 barriers/block). Prefetch staggered:
// next tile's K issued right after the barrier, next tile's V issued between
// the two compute halves. No-max softmax (S log2-domain, sigma~4, overflow at
// 31 sigma -> no clamp). l via MFMA against ones (lane-local, zero shuffles).
__global__ __launch_bounds__(256) void k_attn(const unsigned short* __restrict__ qt,
                                              const unsigned short* __restrict__ kt,
                                              const unsigned short* __restrict__ vt,
                                              unsigned short* __restrict__ abuf) {
  __shared__ __align__(16) unsigned short Ks[2][128 * 64];
  __shared__ __align__(16) unsigned short Vs[2][128 * 64];
  const int bid = blockIdx.x;                  // 512 blocks
  const int bh = (bid & 7) * 8 + (bid >> 6);   // all 8 t-blocks of a bh on one XCD
  const int tb = (bid >> 3) & 7;
  const int tid = threadIdx.x, lane = tid & 63, w = tid >> 6;
  const int lo = lane & 15, g = lane >> 4;
  const int t0 = tb * 128 + w * 32;            // this wave's 32 t-rows
  const unsigned short* qb = qt + (size_t)bh * NL * ND;

  // staging offsets for a 128x64 tile (K row-chunk XOR swizzle, V linear slots)
  int koff[4], voff[4];
#pragma unroll
  for (int r = 0; r < 4; ++r) {
    int c = (r * 4 + w) * 64 + lane;
    int row = c >> 3, lc = (c & 7) ^ (row & 7);
    koff[r] = row * ND + lc * 8;
    voff[r] = c * 8;
  }
  // K-frag base: addr(hh, sblk, ks) = hh*4096 + sblk*1024 + lo*64 + ((ks*4+g)^(lo&7))*8
  const int e0 = lo * 64 + ((g ^ (lo & 7)) * 8);
  const int e1 = lo * 64 + (((4 + g) ^ (lo & 7)) * 8);
  // V-frag base: addr(hh, sblk, ci) = hh*4096 + sblk*1024 + ci*64 + g*256 + lo*4
  const int vbase = g * 256 + lo * 4;

  const unsigned short* kst = kt + (size_t)bh * NL * ND;
  const unsigned short* vst = vt + (size_t)bh * NL * ND;

  bf16x8 qf[2][2];
#pragma unroll
  for (int h = 0; h < 2; ++h)
#pragma unroll
    for (int ks = 0; ks < 2; ++ks)
      qf[h][ks] = *(const bf16x8*)&qb[(size_t)(t0 + h * 16 + lo) * ND + ks * 32 + g * 8];

  bf16x4 vones;
#pragma unroll
  for (int j = 0; j < 4; ++j) vones[j] = (short)0x3F80;   // bf16 1.0

  f32x4 pv[2][4];
#pragma unroll
  for (int h = 0; h < 2; ++h)
#pragma unroll
    for (int ci = 0; ci < 4; ++ci) pv[h][ci] = (f32x4){0.f, 0.f, 0.f, 0.f};
  f32x4 lacc[2];
  lacc[0] = (f32x4){0.f, 0.f, 0.f, 0.f};
  lacc[1] = (f32x4){0.f, 0.f, 0.f, 0.f};

  // prologue: stage tile 0 (128 s-rows) into buffer 0
#pragma unroll
  for (int r = 0; r < 4; ++r) {
    gl_lds16(kst + koff[r], &Ks[0][(r * 4 + w) * 512]);
    gl_lds16(vst + voff[r], &Vs[0][(r * 4 + w) * 512]);
  }
  kst += 8192; vst += 8192;

#define ATTN_HALF(BUF, HH)                                                    \
  {                                                                           \
    f32x4 sacc[2][4];                                                         \
    _Pragma("unroll")                                                         \
    for (int h = 0; h < 2; ++h)                                               \
      _Pragma("unroll")                                                       \
      for (int sblk = 0; sblk < 4; ++sblk)                                    \
        sacc[h][sblk] = (f32x4){0.f, 0.f, 0.f, 0.f};                          \
    __builtin_amdgcn_s_setprio(1);                                            \
    _Pragma("unroll")                                                         \
    for (int sblk = 0; sblk < 4; ++sblk) {                                    \
      bf16x8 kf = *(const bf16x8*)&Ks[BUF][(HH) * 4096 + sblk * 1024 + e0];   \
      sacc[0][sblk] = MFMA16(kf, qf[0][0], sacc[0][sblk]);                    \
      sacc[1][sblk] = MFMA16(kf, qf[1][0], sacc[1][sblk]);                    \
    }                                                                         \
    _Pragma("unroll")                                                         \
    for (int sblk = 0; sblk < 4; ++sblk) {                                    \
      bf16x8 kf = *(const bf16x8*)&Ks[BUF][(HH) * 4096 + sblk * 1024 + e1];   \
      sacc[0][sblk] = MFMA16(kf, qf[0][1], sacc[0][sblk]);                    \
      sacc[1][sblk] = MFMA16(kf, qf[1][1], sacc[1][sblk]);                    \
    }                                                                         \
    __builtin_amdgcn_s_setprio(0);                                            \
    _Pragma("unroll")                                                         \
    for (int sblk = 0; sblk < 4; ++sblk) {                                    \
      float a0 = EXP2F(sacc[0][sblk][0]);                                     \
      float a1 = EXP2F(sacc[0][sblk][1]);                                     \
      float a2 = EXP2F(sacc[0][sblk][2]);                                     \
      float a3 = EXP2F(sacc[0][sblk][3]);                                     \
      bf16x4 pf0;                                                             \
      pf0[0] = f2bf_h(a0); pf0[1] = f2bf_h(a1);                               \
      pf0[2] = f2bf_h(a2); pf0[3] = f2bf_h(a3);                               \
      float b0 = EXP2F(sacc[1][sblk][0]);                                     \
      float b1 = EXP2F(sacc[1][sblk][1]);                                     \
      float b2 = EXP2F(sacc[1][sblk][2]);                                     \
      float b3 = EXP2F(sacc[1][sblk][3]);                                     \
      bf16x4 pf1;                                                             \
      pf1[0] = f2bf_h(b0); pf1[1] = f2bf_h(b1);                               \
      pf1[2] = f2bf_h(b2); pf1[3] = f2bf_h(b3);                               \
      __builtin_amdgcn_s_setprio(1);                                          \
      lacc[0] = mfma_k16(pf0, vones, lacc[0]);                                \
      lacc[1] = mfma_k16(pf1, vones, lacc[1]);                                \
      _Pragma("unroll")                                                       \
      for (int ci = 0; ci < 4; ++ci) {                                        \
        bf16x4 vf = *(const bf16x4*)                                          \
            &Vs[BUF][(HH) * 4096 + sblk * 1024 + ci * 64 + vbase];            \
        pv[0][ci] = mfma_k16(pf0, vf, pv[0][ci]);                             \
        pv[1][ci] = mfma_k16(pf1, vf, pv[1][ci]);                             \
      }                                                                       \
      __builtin_amdgcn_s_setprio(0);                                          \
    }                                                                         \
  }

#define ATTN_TILE(BUF, LAST)                                                  \
  {                                                                           \
    __syncthreads();                                                          \
    if (!(LAST)) {                                                            \
      _Pragma("unroll")                                                       \
      for (int r = 0; r < 4; ++r)                                             \
        gl_lds16(kst + koff[r], &Ks[(BUF) ^ 1][(r * 4 + w) * 512]);           \
    }                                                                         \
    ATTN_HALF(BUF, 0);                                                        \
    if (!(LAST)) {                                                            \
      _Pragma("unroll")                                                       \
      for (int r = 0; r < 4; ++r)                                             \
        gl_lds16(vst + voff[r], &Vs[(BUF) ^ 1][(r * 4 + w) * 512]);           \
      kst += 8192; vst += 8192;                                               \
    }                                                                         \
    ATTN_HALF(BUF, 1);                                                        \
  }

  for (int it = 0; it < 8; it += 2) {
    ATTN_TILE(0, false);
    ATTN_TILE(1, it == 6);
  }
#undef ATTN_TILE
#undef ATTN_HALF

  // epilogue: lacc[h][i] is the row-sum for t-row t0+h*16+g*4+i (lane-local).
#pragma unroll
  for (int h = 0; h < 2; ++h) {
    float li[4];
#pragma unroll
    for (int i = 0; i < 4; ++i) li[i] = 1.0f / lacc[h][i];
#pragma unroll
    for (int ci = 0; ci < 4; ++ci)
#pragma unroll
      for (int i = 0; i < 4; ++i) {
        int tl = t0 + h * 16 + g * 4 + i;
        abuf[((size_t)bh * NL + tl) * ND + ci * 16 + lo] = f2bf_h(pv[h][ci][i] * li[i]);
      }
  }
}

// ---------------- K4: proj GEMM + bias + residual (BK=64 dbuf, 1 barrier/step) ----
// Grid is 256 blocks = 1/CU -> no TLP to hide barrier drains; the staggered
// dbuf pipeline is the only latency-hiding mechanism. 8 barriers instead of 16.
__global__ __launch_bounds__(256) void k_proj(const unsigned short* __restrict__ abuf,
                                              const unsigned short* __restrict__ pwb,
                                              const float* __restrict__ pb,
                                              const float* __restrict__ x,
                                              float* __restrict__ out) {
  __shared__ __align__(16) unsigned short As[2][128 * 64];
  __shared__ __align__(16) unsigned short Bs[2][128 * 64];
  const int m0 = blockIdx.x * 128;  // o
  const int n0 = blockIdx.y * 128;  // l
  const int b = blockIdx.z;
  const int tid = threadIdx.x, lane = tid & 63, w = tid >> 6;
  const int wr = w >> 1, wc = w & 1;
  const int lo = lane & 15, g = lane >> 4;

  int aoff[4], boff[4];
#pragma unroll
  for (int r = 0; r < 4; ++r) {
    int c = (r * 4 + w) * 64 + lane;
    int row = c >> 3, lc = (c & 7) ^ (row & 7);
    aoff[r] = row * NC + lc * 8;
    boff[r] = row * ND + lc * 8;
  }
  const unsigned short* Ap = pwb + (size_t)m0 * NC;
  const unsigned short* Bp = abuf + ((size_t)(b * NHD) * NL + n0) * ND;  // +head*NL*ND per step

  f32x4 acc[4][4];
#pragma unroll
  for (int mi = 0; mi < 4; ++mi)
#pragma unroll
    for (int ni = 0; ni < 4; ++ni) acc[mi][ni] = (f32x4){0.f, 0.f, 0.f, 0.f};

  // prologue: stage k-step 0 into buffer 0
#pragma unroll
  for (int r = 0; r < 4; ++r) {
    gl_lds16(Ap + aoff[r], &As[0][(r * 4 + w) * 512]);
    gl_lds16(Bp + boff[r], &Bs[0][(r * 4 + w) * 512]);
  }
  Ap += 64; Bp += (size_t)NL * ND;

#define PROJ_KS(BUF, KS)                                                      \
  {                                                                           \
    bf16x8 af[4], bfr[4];                                                     \
    _Pragma("unroll")                                                         \
    for (int mi = 0; mi < 4; ++mi) {                                          \
      int row = wr * 64 + mi * 16 + lo;                                       \
      int ph = (g + (KS) * 4) ^ (row & 7);                                    \
      af[mi] = *(const bf16x8*)&As[BUF][row * 64 + ph * 8];                   \
    }                                                                         \
    _Pragma("unroll")                                                         \
    for (int ni = 0; ni < 4; ++ni) {                                          \
      int row = wc * 64 + ni * 16 + lo;                                       \
      int ph = (g + (KS) * 4) ^ (row & 7);                                    \
      bfr[ni] = *(const bf16x8*)&Bs[BUF][row * 64 + ph * 8];                  \
    }                                                                         \
    _Pragma("unroll")                                                         \
    for (int mi = 0; mi < 4; ++mi)                                            \
      _Pragma("unroll")                                                       \
      for (int ni = 0; ni < 4; ++ni)                                          \
        acc[mi][ni] = MFMA16(af[mi], bfr[ni], acc[mi][ni]);                   \
  }

#define PROJ_STEP(BUF, LAST)                                                  \
  {                                                                           \
    __syncthreads();                                                          \
    if (!(LAST)) {                                                            \
      _Pragma("unroll")                                                       \
      for (int r = 0; r < 4; ++r)                                             \
        gl_lds16(Ap + aoff[r], &As[(BUF) ^ 1][(r * 4 + w) * 512]);            \
    }                                                                         \
    PROJ_KS(BUF, 0);                                                          \
    if (!(LAST)) {                                                            \
      _Pragma("unroll")                                                       \
      for (int r = 0; r < 4; ++r)                                             \
        gl_lds16(Bp + boff[r], &Bs[(BUF) ^ 1][(r * 4 + w) * 512]);            \
      Ap += 64; Bp += (size_t)NL * ND;                                        \
    }                                                                         \
    PROJ_KS(BUF, 1);                                                          \
  }

  for (int it = 0; it < 8; it += 2) {
    PROJ_STEP(0, false);
    PROJ_STEP(1, it == 6);
  }
#undef PROJ_STEP
#undef PROJ_KS

#pragma unroll
  for (int mi = 0; mi < 4; ++mi)
#pragma unroll
    for (int i = 0; i < 4; ++i) {
      int o = m0 + wr * 64 + mi * 16 + g * 4 + i;
      float pbv = pb[o];
#pragma unroll
      for (int ni = 0; ni < 4; ++ni) {
        int l = n0 + wc * 64 + ni * 16 + lo;
        size_t idx = ((size_t)b * NC + o) * NL + l;
        out[idx] = x[idx] + acc[mi][ni][i] + pbv;
      }
    }
}

extern "C" void kernel_launch(void* const* d_in, const int* in_sizes, int n_in,
                              void* d_out, int out_size, void* d_ws, size_t ws_size,
                              hipStream_t stream) {
  const float* x    = (const float*)d_in[0];
  const float* nw   = (const float*)d_in[1];
  const float* nb   = (const float*)d_in[2];
  const float* qkvw = (const float*)d_in[3];
  const float* qkvb = (const float*)d_in[4];
  const float* pw   = (const float*)d_in[5];
  const float* pb   = (const float*)d_in[6];
  float* out = (float*)d_out;

  char* ws = (char*)d_ws;
  unsigned short* xnt  = (unsigned short*)(ws);
  unsigned short* abuf = (unsigned short*)(ws);             // overlay (xnt dead after k_qkv)
  unsigned short* qwb  = (unsigned short*)(ws + 8388608);
  unsigned short* pwb  = (unsigned short*)(ws + 9961472);
  unsigned short* qt   = (unsigned short*)(ws + 10485760);
  unsigned short* kt   = (unsigned short*)(ws + 18874368);
  unsigned short* vt   = (unsigned short*)(ws + 27262976);

  k_pre<<<1280, 256, 0, stream>>>(x, nw, nb, qkvw, pw, xnt, qwb, pwb);
  k_qkv<<<dim3(8, 12, 8), 256, 0, stream>>>(xnt, qwb, qkvb, qt, kt, vt);
  k_attn<<<512, 256, 0, stream>>>(qt, kt, vt, abuf);
  k_proj<<<dim3(4, 8, 8), 256, 0, stream>>>(abuf, pwb, pb, x, out);
}